// Round 4
// baseline (965.024 us; speedup 1.0000x reference)
//
#include <hip/hip_runtime.h>

// GATCL: 2-head GAT (N=8192, D=256) + feature conv (K=129) + GAT(D=128) + 2 MLPs + pair dots.
// R4: R3 with the k_gemm_h hT-store coverage bug fixed (each thread now stores 4x uint4,
// full 128x64 tile). Pipelined flash aggregation, XOR-swizzled LDS, fused prep/embed.

typedef _Float16 f16;
typedef _Float16 f16x8 __attribute__((ext_vector_type(8)));
typedef float f32x4 __attribute__((ext_vector_type(4)));

#define DEV __device__ __forceinline__
#define L2E 1.4426950408889634f
#define NN 8192
#define IND 768
#define D1 256
#define DT 512
#define D2 128
#define KC 129
#define EPAIRS 100000

#if __has_builtin(__builtin_amdgcn_exp2f)
#define EXP2(x) __builtin_amdgcn_exp2f(x)
#else
#define EXP2(x) exp2f(x)
#endif

DEV float eluf(float x){ return x > 0.f ? x : EXP2(x*L2E) - 1.f; }

// ---------------- P: fused prep = pack(adj->bits) + cast(x->fp16) + Wt transpose ----------------
__global__ __launch_bounds__(256) void k_prep(
    const int4* __restrict__ adj4, unsigned* __restrict__ maskw,
    const float* __restrict__ x, f16* __restrict__ x16,
    const float* __restrict__ W, f16* __restrict__ Wt){
  int b = blockIdx.x, t = threadIdx.x;
  if (b < 65536){
    int idx = b*256 + t;
    int4 v = adj4[idx];
    unsigned n = (unsigned)(v.x > 0) | ((unsigned)(v.y > 0) << 1)
               | ((unsigned)(v.z > 0) << 2) | ((unsigned)(v.w > 0) << 3);
    n |= __shfl_xor(n, 1) << 4;
    n |= __shfl_xor(n, 2) << 8;
    n |= __shfl_xor(n, 4) << 16;
    if ((t & 7) == 0) maskw[idx >> 3] = n;
  } else if (b < 65536 + 6144){
    int i = ((b - 65536)*256 + t)*4;
    float4 v = *(const float4*)(x + i);
    union { f16 h[4]; uint2 u; } p;
    p.h[0]=(f16)v.x; p.h[1]=(f16)v.y; p.h[2]=(f16)v.z; p.h[3]=(f16)v.w;
    *(uint2*)(x16 + i) = p.u;
  } else {
    int np = b - 71680; int h = np >> 8, d = np & 255;
    for (int k = t; k < IND; k += 256)
      Wt[(size_t)np*IND + k] = (f16)W[((size_t)h*IND + k)*D1 + d];
  }
}

// ---------------- G1: h = x @ W' (8192x512), swizzled LDS, prefetch, coalesced hT store ----------------
__global__ __launch_bounds__(256) void k_gemm_h(
    const f16* __restrict__ x16, const f16* __restrict__ Wt,
    const float* __restrict__ head_a,
    f16* __restrict__ hT, float* __restrict__ wh1, float* __restrict__ wh2){
  __shared__ f16 SM[(64 + 128)*64];        // As = SM[0:64), Bs = SM[64*64 ...)
  f16* As = SM;
  f16* Bs = SM + 64*64;
  int m0 = blockIdx.x*64, n0 = blockIdx.y*128;
  int t = threadIdx.x, lane = t & 63, w = t >> 6;
  int wi = w >> 1, wd = w & 1;
  int rm = lane & 15, q4 = lane >> 4;
  int drb = t >> 3, gofs = (t & 7)*8;
  int sg8 = (((t & 7) ^ ((t >> 3) & 7))*8);
  f32x4 acc[2][4] = {};
  uint4 preA[2], preB[4];
#pragma unroll
  for (int p = 0; p < 2; p++)
    preA[p] = *(const uint4*)&x16[(size_t)(m0 + p*32 + drb)*IND + gofs];
#pragma unroll
  for (int p = 0; p < 4; p++)
    preB[p] = *(const uint4*)&Wt[(size_t)(n0 + p*32 + drb)*IND + gofs];
  for (int k0 = 0; k0 < IND; k0 += 64){
    __syncthreads();
#pragma unroll
    for (int p = 0; p < 2; p++) *(uint4*)&As[(p*32 + drb)*64 + sg8] = preA[p];
#pragma unroll
    for (int p = 0; p < 4; p++) *(uint4*)&Bs[(p*32 + drb)*64 + sg8] = preB[p];
    __syncthreads();
    if (k0 + 64 < IND){
#pragma unroll
      for (int p = 0; p < 2; p++)
        preA[p] = *(const uint4*)&x16[(size_t)(m0 + p*32 + drb)*IND + k0 + 64 + gofs];
#pragma unroll
      for (int p = 0; p < 4; p++)
        preB[p] = *(const uint4*)&Wt[(size_t)(n0 + p*32 + drb)*IND + k0 + 64 + gofs];
    }
#pragma unroll
    for (int ks = 0; ks < 2; ks++){
      int gl = ks*4 + q4;
      int r0 = wi*32 + rm, r1 = wi*32 + 16 + rm;
      f16x8 a0 = *(const f16x8*)&As[r0*64 + ((gl ^ (r0 & 7))*8)];
      f16x8 a1 = *(const f16x8*)&As[r1*64 + ((gl ^ (r1 & 7))*8)];
#pragma unroll
      for (int fn = 0; fn < 4; fn++){
        int rb = wd*64 + fn*16 + rm;
        f16x8 b = *(const f16x8*)&Bs[rb*64 + ((gl ^ (rb & 7))*8)];
        acc[0][fn] = __builtin_amdgcn_mfma_f32_16x16x32_f16(a0, b, acc[0][fn], 0, 0, 0);
        acc[1][fn] = __builtin_amdgcn_mfma_f32_16x16x32_f16(a1, b, acc[1][fn], 0, 0, 0);
      }
    }
  }
  int quad = lane >> 4, cl = lane & 15;
  int head = n0 >> 8;
  // ---- transpose C into LDS (T[d][i], stride 72) then coalesced hT store ----
  f16* T = SM;   // 128*72 = 9216 f16 <= 12288
  __syncthreads();
#pragma unroll
  for (int fi = 0; fi < 2; fi++)
#pragma unroll
    for (int fn = 0; fn < 4; fn++){
      int d = wd*64 + fn*16 + cl;
      int i = wi*32 + fi*16 + quad*4;
      union { f16 h[4]; uint2 u; } pk;
#pragma unroll
      for (int reg = 0; reg < 4; reg++) pk.h[reg] = (f16)acc[fi][fn][reg];
      *(uint2*)&T[d*72 + i] = pk.u;
    }
  __syncthreads();
  { int row = t >> 1, half = t & 1;
    const f16* src = &T[row*72 + half*32];
    f16* dst = &hT[(size_t)(n0 + row)*NN + m0 + half*32];
#pragma unroll
    for (int q = 0; q < 4; q++)
      *(uint4*)&dst[q*8] = *(const uint4*)&src[q*8];
  }
  // ---- wh1/wh2 partial dots ----
  float a1v[4], a2v[4];
#pragma unroll
  for (int fn = 0; fn < 4; fn++){
    int d = (n0 & 255) + wd*64 + fn*16 + cl;
    a1v[fn] = head_a[head*DT + d];
    a2v[fn] = head_a[head*DT + D1 + d];
  }
  float p1[2][4], p2[2][4];
#pragma unroll
  for (int fi = 0; fi < 2; fi++)
#pragma unroll
    for (int reg = 0; reg < 4; reg++){
      float s1 = 0.f, s2 = 0.f;
#pragma unroll
      for (int fn = 0; fn < 4; fn++){ s1 += acc[fi][fn][reg]*a1v[fn]; s2 += acc[fi][fn][reg]*a2v[fn]; }
      p1[fi][reg] = s1; p2[fi][reg] = s2;
    }
#pragma unroll
  for (int o = 1; o < 16; o <<= 1){
#pragma unroll
    for (int fi = 0; fi < 2; fi++)
#pragma unroll
      for (int reg = 0; reg < 4; reg++){
        p1[fi][reg] += __shfl_xor(p1[fi][reg], o);
        p2[fi][reg] += __shfl_xor(p2[fi][reg], o);
      }
  }
  if (cl == 0){
#pragma unroll
    for (int fi = 0; fi < 2; fi++)
#pragma unroll
      for (int reg = 0; reg < 4; reg++){
        int mg = m0 + wi*32 + fi*16 + quad*4 + reg;
        atomicAdd(&wh1[head*NN + mg], p1[fi][reg]);
        atomicAdd(&wh2[head*NN + mg], p2[fi][reg]);
      }
  }
}

// ---------------- R: rowterms = colterms + per-head global max of wh2 ----------------
__global__ __launch_bounds__(256) void k_rowterms(const float* __restrict__ wh2,
    float* __restrict__ c1, float* __restrict__ c2, unsigned* __restrict__ gmax){
  int i = blockIdx.x*256 + threadIdx.x;      // 0..16383
  float v = wh2[i];
  c1[i] = v*L2E; c2[i] = 0.2f*v*L2E;
  float m = v;
#pragma unroll
  for (int o = 32; o > 0; o >>= 1) m = fmaxf(m, __shfl_xor(m, o));
  if ((threadIdx.x & 63) == 0){
    unsigned bbits = __float_as_uint(m);
    unsigned enc = (bbits & 0x80000000u) ? ~bbits : (bbits | 0x80000000u);
    atomicMax(gmax + (i >> 13), enc);
  }
}

// ---------------- A1: head GAT aggregation, pipelined, swizzled ----------------
__global__ __launch_bounds__(256, 2) void k_agg_head(
    const f16* __restrict__ hT, const unsigned* __restrict__ maskw,
    const float* __restrict__ wh1, const float* __restrict__ c1,
    const float* __restrict__ c2, const unsigned* __restrict__ gmaxp,
    float* __restrict__ num, float* __restrict__ den){
  __shared__ f16 Hs[256*64];
  __shared__ f16 Ws[64*64];
  int head = blockIdx.z;
  int i0 = blockIdx.x*64;
  int jbase = blockIdx.y*4096;
  const f16* hTh = hT + (size_t)head*D1*NN;
  int t = threadIdx.x, lane = t & 63, w = t >> 6;
  int rm = lane & 15, q4 = lane >> 4;
  int si = t >> 2, sjq = (t & 3)*16;
  unsigned e = gmaxp[head];
  float gmax = __uint_as_float((e & 0x80000000u) ? (e ^ 0x80000000u) : ~e);
  float u = wh1[head*NN + i0 + si];
  float sm = u + gmax;
  float M = (sm > 0.f ? sm : 0.2f*sm)*L2E;   // leaky(wh1+gmax) in log2 units
  float ra = u*L2E - M, rb = 0.2f*u*L2E - M;
  const float* c1h = c1 + head*NN;
  const float* c2h = c2 + head*NN;
  const unsigned* mrowp = maskw + (size_t)(i0 + si)*(NN/32);
  int drb = t >> 3, gofs = (t & 7)*8;
  int sg8 = (((t & 7) ^ ((t >> 3) & 7))*8);
  int wg0 = (t & 3)*2;
  float rden = 0.f;
  f32x4 acc[4][4] = {};
  uint4 pre[8];
#pragma unroll
  for (int p = 0; p < 8; p++)
    pre[p] = *(const uint4*)&hTh[(size_t)(p*32 + drb)*NN + jbase + gofs];
  for (int j0 = 0; j0 < 4096; j0 += 64){
    int jg = jbase + j0;
    __syncthreads();
#pragma unroll
    for (int p = 0; p < 8; p++) *(uint4*)&Hs[(p*32 + drb)*64 + sg8] = pre[p];
    // scores (global c1/c2/mask reads; independent of staging)
    unsigned mb = mrowp[(unsigned)(jg + sjq) >> 5] >> (sjq & 31);
    float ca[16], cb[16];
#pragma unroll
    for (int k = 0; k < 4; k++){
      float4 va = *(const float4*)&c1h[jg + sjq + 4*k];
      float4 vb = *(const float4*)&c2h[jg + sjq + 4*k];
      ca[4*k]=va.x; ca[4*k+1]=va.y; ca[4*k+2]=va.z; ca[4*k+3]=va.w;
      cb[4*k]=vb.x; cb[4*k+1]=vb.y; cb[4*k+2]=vb.z; cb[4*k+3]=vb.w;
    }
    f16x8 wlo, whi;
    float dsum = 0.f;
#pragma unroll
    for (int q = 0; q < 16; q++){
      float s1 = ra + ca[q], s2 = rb + cb[q];
      float wv = EXP2(fmaxf(s1, s2));          // exp(leaky(s)-m) <= 1
      wv = ((mb >> q) & 1u) ? wv : 0.f;
      dsum += wv;
      if (q < 8) wlo[q] = (f16)wv; else whi[q - 8] = (f16)wv;
    }
    *(f16x8*)&Ws[si*64 + ((wg0       ^ (si & 7))*8)] = wlo;
    *(f16x8*)&Ws[si*64 + (((wg0 + 1) ^ (si & 7))*8)] = whi;
    dsum += __shfl_xor(dsum, 1);
    dsum += __shfl_xor(dsum, 2);
    rden += dsum;
    __syncthreads();
    if (j0 + 64 < 4096){
#pragma unroll
      for (int p = 0; p < 8; p++)
        pre[p] = *(const uint4*)&hTh[(size_t)(p*32 + drb)*NN + jg + 64 + gofs];
    }
#pragma unroll
    for (int ks = 0; ks < 2; ks++){
      int gl = ks*4 + q4;
      f16x8 a[4], b[4];
#pragma unroll
      for (int mi = 0; mi < 4; mi++){
        int row = mi*16 + rm;
        a[mi] = *(const f16x8*)&Ws[row*64 + ((gl ^ (row & 7))*8)];
      }
#pragma unroll
      for (int fn = 0; fn < 4; fn++){
        int row = w*64 + fn*16 + rm;
        b[fn] = *(const f16x8*)&Hs[row*64 + ((gl ^ (row & 7))*8)];
      }
#pragma unroll
      for (int mi = 0; mi < 4; mi++)
#pragma unroll
        for (int fn = 0; fn < 4; fn++)
          acc[mi][fn] = __builtin_amdgcn_mfma_f32_16x16x32_f16(a[mi], b[fn], acc[mi][fn], 0, 0, 0);
    }
  }
  if ((t & 3) == 0) atomicAdd(&den[head*NN + i0 + si], rden);
  int quad = lane >> 4, cl = lane & 15;
#pragma unroll
  for (int mi = 0; mi < 4; mi++)
#pragma unroll
    for (int fn = 0; fn < 4; fn++){
      int rr = i0 + mi*16 + quad*4;
      int dc = w*64 + fn*16 + cl;
#pragma unroll
      for (int reg = 0; reg < 4; reg++)
        atomicAdd(&num[((size_t)head*NN + rr + reg)*D1 + dc], acc[mi][fn][reg]);
    }
}

// ---------------- E1: merge heads -> z -> conv -> gT(fp16) + wc1L/wc2L ----------------
__global__ __launch_bounds__(256) void k_merge_conv(
    const float* __restrict__ num, const float* __restrict__ den,
    const float* __restrict__ head_b, const float* __restrict__ conv_w,
    const float* __restrict__ conv_cb, const float* __restrict__ conv_a,
    f16* __restrict__ gT, float* __restrict__ wc1L, float* __restrict__ wc2L){
  __shared__ float zrow[2][256];
  __shared__ float cw[KC];
  __shared__ float ca[256];
  __shared__ float red[2][2];
  __shared__ float red2[2][2][2];
  int t = threadIdx.x, g = t >> 7, c = t & 127;
  int r = blockIdx.x*2 + g;
  if (t < KC) cw[t] = conv_w[t];
  ca[t] = conv_a[t];
  float zv0 = 0.f, zv1 = 0.f;
#pragma unroll
  for (int h = 0; h < 2; h++){
    const float* nr = num + ((size_t)h*NN + r)*D1;
    float inv = 1.f / den[h*NN + r];
    float e0 = eluf(nr[c]*inv);
    float e1 = eluf(nr[c + 128]*inv);
    float ss = e0*e0 + e1*e1;
#pragma unroll
    for (int o = 32; o > 0; o >>= 1) ss += __shfl_xor(ss, o);
    if ((t & 63) == 0) red[g][(t >> 6) & 1] = ss;
    __syncthreads();
    float invn = 1.f / fmaxf(sqrtf(red[g][0] + red[g][1]), 1e-12f);
    zv0 += e0*invn + head_b[h*D1 + c];
    zv1 += e1*invn + head_b[h*D1 + 128 + c];
    __syncthreads();
  }
  zrow[g][c]       = eluf(0.5f*zv0);
  zrow[g][c + 128] = eluf(0.5f*zv1);
  __syncthreads();
  float s = conv_cb[0];
  for (int k = 0; k < KC; k++) s += zrow[g][c + k]*cw[k];
  gT[(size_t)c*NN + r] = (f16)s;
  float p1 = s*ca[c], p2 = s*ca[128 + c];
#pragma unroll
  for (int o = 32; o > 0; o >>= 1){ p1 += __shfl_xor(p1, o); p2 += __shfl_xor(p2, o); }
  if ((t & 63) == 0){ red2[g][(t >> 6) & 1][0] = p1; red2[g][(t >> 6) & 1][1] = p2; }
  __syncthreads();
  if ((t & 127) == 0){
    wc1L[r] = (red2[g][0][0] + red2[g][1][0])*L2E;
    wc2L[r] = (red2[g][0][1] + red2[g][1][1])*L2E;
  }
}

// ---------------- A2: conv GAT aggregation (elu scores, m=0), pipelined, swizzled ----------------
__global__ __launch_bounds__(256, 2) void k_agg_conv(
    const f16* __restrict__ gT, const unsigned* __restrict__ maskw,
    const float* __restrict__ wc1L, const float* __restrict__ wc2L,
    float* __restrict__ num, float* __restrict__ den){
  __shared__ f16 Hs[128*64];
  __shared__ f16 Ws[64*64];
  int i0 = blockIdx.x*64;
  int jbase = blockIdx.y*1024;
  int t = threadIdx.x, lane = t & 63, w = t >> 6;
  int rm = lane & 15, q4 = lane >> 4;
  int si = t >> 2, sjq = (t & 3)*16;
  float ra = wc1L[i0 + si];
  const unsigned* mrowp = maskw + (size_t)(i0 + si)*(NN/32);
  int drb = t >> 3, gofs = (t & 7)*8;
  int sg8 = (((t & 7) ^ ((t >> 3) & 7))*8);
  int wg0 = (t & 3)*2;
  float rden = 0.f;
  f32x4 acc[4][2] = {};
  uint4 pre[4];
#pragma unroll
  for (int p = 0; p < 4; p++)
    pre[p] = *(const uint4*)&gT[(size_t)(p*32 + drb)*NN + jbase + gofs];
  for (int j0 = 0; j0 < 1024; j0 += 64){
    int jg = jbase + j0;
    __syncthreads();
#pragma unroll
    for (int p = 0; p < 4; p++) *(uint4*)&Hs[(p*32 + drb)*64 + sg8] = pre[p];
    unsigned mb = mrowp[(unsigned)(jg + sjq) >> 5] >> (sjq & 31);
    float cc[16];
#pragma unroll
    for (int k = 0; k < 4; k++){
      float4 va = *(const float4*)&wc2L[jg + sjq + 4*k];
      cc[4*k]=va.x; cc[4*k+1]=va.y; cc[4*k+2]=va.z; cc[4*k+3]=va.w;
    }
    f16x8 wlo, whi;
    float dsum = 0.f;
#pragma unroll
    for (int q = 0; q < 16; q++){
      float sL = ra + cc[q];                   // s*log2e
      float t2 = EXP2(sL);                     // e^s
      float wv = sL > 0.f ? t2 : EXP2((t2 - 1.f)*L2E);  // exp(elu(s))
      wv = ((mb >> q) & 1u) ? wv : 0.f;
      dsum += wv;
      if (q < 8) wlo[q] = (f16)wv; else whi[q - 8] = (f16)wv;
    }
    *(f16x8*)&Ws[si*64 + ((wg0       ^ (si & 7))*8)] = wlo;
    *(f16x8*)&Ws[si*64 + (((wg0 + 1) ^ (si & 7))*8)] = whi;
    dsum += __shfl_xor(dsum, 1);
    dsum += __shfl_xor(dsum, 2);
    rden += dsum;
    __syncthreads();
    if (j0 + 64 < 1024){
#pragma unroll
      for (int p = 0; p < 4; p++)
        pre[p] = *(const uint4*)&gT[(size_t)(p*32 + drb)*NN + jg + 64 + gofs];
    }
#pragma unroll
    for (int ks = 0; ks < 2; ks++){
      int gl = ks*4 + q4;
      f16x8 a[4], b[2];
#pragma unroll
      for (int mi = 0; mi < 4; mi++){
        int row = mi*16 + rm;
        a[mi] = *(const f16x8*)&Ws[row*64 + ((gl ^ (row & 7))*8)];
      }
#pragma unroll
      for (int fn = 0; fn < 2; fn++){
        int row = w*32 + fn*16 + rm;
        b[fn] = *(const f16x8*)&Hs[row*64 + ((gl ^ (row & 7))*8)];
      }
#pragma unroll
      for (int mi = 0; mi < 4; mi++)
#pragma unroll
        for (int fn = 0; fn < 2; fn++)
          acc[mi][fn] = __builtin_amdgcn_mfma_f32_16x16x32_f16(a[mi], b[fn], acc[mi][fn], 0, 0, 0);
    }
  }
  if ((t & 3) == 0) atomicAdd(&den[i0 + si], rden);
  int quad = lane >> 4, cl = lane & 15;
#pragma unroll
  for (int mi = 0; mi < 4; mi++)
#pragma unroll
    for (int fn = 0; fn < 2; fn++){
      int rr = i0 + mi*16 + quad*4;
      int dc = w*32 + fn*16 + cl;
#pragma unroll
      for (int reg = 0; reg < 4; reg++)
        atomicAdd(&num[(size_t)(rr + reg)*D2 + dc], acc[mi][fn][reg]);
    }
}

// ---------------- E3: fused embed + two 128->128->64 elu MLPs, 32 rows/block ----------------
__global__ __launch_bounds__(256) void k_mlp(
    const float* __restrict__ numc, const float* __restrict__ denc,
    const float* __restrict__ conv_b,
    const float* __restrict__ fw1, const float* __restrict__ fb1,
    const float* __restrict__ fw2, const float* __restrict__ fb2,
    const float* __restrict__ gw1, const float* __restrict__ gb1,
    const float* __restrict__ gw2, const float* __restrict__ gb2,
    float* __restrict__ tf, float* __restrict__ tg){
  const float* w1 = blockIdx.y ? gw1 : fw1;
  const float* b1 = blockIdx.y ? gb1 : fb1;
  const float* w2 = blockIdx.y ? gw2 : fw2;
  const float* b2 = blockIdx.y ? gb2 : fb2;
  float* out = blockIdx.y ? tg : tf;
  int t = threadIdx.x;
  int c = t & 127, kh = t >> 7;
  int o = t & 63, kh2 = t >> 6;
  int r0 = blockIdx.x*32;
  __shared__ float es[32][132];
  // ---- embed: l2norm(elu(numc/denc)) + conv_b ----
  { int row = t >> 3, c0 = (t & 7)*16;
    float inv = 1.f / denc[r0 + row];
    float ev[16]; float ss = 0.f;
#pragma unroll
    for (int k = 0; k < 4; k++){
      float4 v = *(const float4*)&numc[(size_t)(r0 + row)*D2 + c0 + 4*k];
      float e0 = eluf(v.x*inv), e1 = eluf(v.y*inv), e2 = eluf(v.z*inv), e3 = eluf(v.w*inv);
      ev[4*k]=e0; ev[4*k+1]=e1; ev[4*k+2]=e2; ev[4*k+3]=e3;
      ss += e0*e0 + e1*e1 + e2*e2 + e3*e3;
    }
    ss += __shfl_xor(ss, 1); ss += __shfl_xor(ss, 2); ss += __shfl_xor(ss, 4);
    float invn = 1.f / fmaxf(sqrtf(ss), 1e-12f);
#pragma unroll
    for (int k = 0; k < 16; k++) es[row][c0 + k] = ev[k]*invn + conv_b[c0 + k];
  }
  float rw1[64];
#pragma unroll
  for (int i = 0; i < 64; i++) rw1[i] = w1[(kh*64 + i)*128 + c];
  float rw2[32];
#pragma unroll
  for (int i = 0; i < 32; i++) rw2[i] = w2[(kh2*32 + i)*64 + o];
  float bb1 = b1[c], bb2 = b2[o];
  __shared__ float hidp[2][4][128];
  __shared__ float hid[4][128];
  __shared__ float outp[4][4][64];
  __syncthreads();
  for (int it = 0; it < 8; it++){
    int rb4 = it*4;
#pragma unroll
    for (int g = 0; g < 4; g++){
      float s = 0.f;
#pragma unroll
      for (int i = 0; i < 64; i++) s += es[rb4 + g][kh*64 + i]*rw1[i];
      hidp[kh][g][c] = s;
    }
    __syncthreads();
#pragma unroll
    for (int gg = 0; gg < 2; gg++){
      int g = kh + 2*gg;
      hid[g][c] = eluf(bb1 + hidp[0][g][c] + hidp[1][g][c]);
    }
    __syncthreads();
#pragma unroll
    for (int g = 0; g < 4; g++){
      float s = 0.f;
#pragma unroll
      for (int i = 0; i < 32; i++) s += hid[g][kh2*32 + i]*rw2[i];
      outp[kh2][g][o] = s;
    }
    __syncthreads();
    { int g = t >> 6;
      out[(size_t)(r0 + rb4 + g)*64 + o] =
        eluf(bb2 + outp[0][g][o] + outp[1][g][o] + outp[2][g][o] + outp[3][g][o]); }
    __syncthreads();
  }
}

// ---------------- E4: pred = rowwise dot of gathered tf/tg ----------------
__global__ __launch_bounds__(256) void k_pred(
    const int* __restrict__ ts, const float4* __restrict__ tf4,
    const float4* __restrict__ tg4, float* __restrict__ out){
  int p = blockIdx.x*16 + (threadIdx.x >> 4);
  int l = threadIdx.x & 15;
  int i = ts[2*p], j = ts[2*p + 1];
  float4 a = tf4[(size_t)i*16 + l], b = tg4[(size_t)j*16 + l];
  float v = a.x*b.x + a.y*b.y + a.z*b.z + a.w*b.w;
  v += __shfl_xor(v, 1); v += __shfl_xor(v, 2);
  v += __shfl_xor(v, 4); v += __shfl_xor(v, 8);
  if (l == 0) out[p] = v;
}

// ---------------- workspace layout ----------------
#define OFF_MASK  ((size_t)0)
#define OFF_X16   ((size_t)8388608)
#define OFF_WT16  ((size_t)20971520)
#define OFF_HT16  ((size_t)21757952)
#define OFF_WH1   ((size_t)30146560)
#define OFF_WH2   ((size_t)30212096)
#define OFF_GMAX  ((size_t)30277632)
#define OFF_C1    ((size_t)30277888)
#define OFF_C2    ((size_t)30343424)
#define OFF_NUM1  ((size_t)30408960)
#define OFF_DEN1  ((size_t)47186176)
#define OFF_GT16  ((size_t)47251712)
#define OFF_WC1L  ((size_t)49348864)
#define OFF_WC2L  ((size_t)49381632)
#define OFF_NUMC  ((size_t)49414400)
#define OFF_DENC  ((size_t)53608704)
#define OFF_TF    ((size_t)53641472)
#define OFF_TG    ((size_t)55738624)

extern "C" void kernel_launch(void* const* d_in, const int* in_sizes, int n_in,
                              void* d_out, int out_size, void* d_ws, size_t ws_size,
                              hipStream_t stream){
  const float* x      = (const float*)d_in[0];
  const int*   adj    = (const int*)d_in[1];
  const int*   ts     = (const int*)d_in[2];
  const float* head_W = (const float*)d_in[3];
  const float* head_a = (const float*)d_in[4];
  const float* head_b = (const float*)d_in[5];
  const float* conv_w = (const float*)d_in[6];
  const float* conv_cb= (const float*)d_in[7];
  const float* conv_a = (const float*)d_in[8];
  const float* conv_b = (const float*)d_in[9];
  const float* tf_w1  = (const float*)d_in[10];
  const float* tf_b1  = (const float*)d_in[11];
  const float* tf_w2  = (const float*)d_in[12];
  const float* tf_b2  = (const float*)d_in[13];
  const float* tg_w1  = (const float*)d_in[14];
  const float* tg_b1  = (const float*)d_in[15];
  const float* tg_w2  = (const float*)d_in[16];
  const float* tg_b2  = (const float*)d_in[17];
  float* outp = (float*)d_out;
  char* ws = (char*)d_ws;

  unsigned* maskw = (unsigned*)(ws + OFF_MASK);
  f16*   x16   = (f16*)(ws + OFF_X16);
  f16*   Wt16  = (f16*)(ws + OFF_WT16);
  f16*   hT16  = (f16*)(ws + OFF_HT16);
  float* wh1   = (float*)(ws + OFF_WH1);
  float* wh2   = (float*)(ws + OFF_WH2);
  unsigned* gmax = (unsigned*)(ws + OFF_GMAX);
  float* c1    = (float*)(ws + OFF_C1);
  float* c2    = (float*)(ws + OFF_C2);
  float* num1  = (float*)(ws + OFF_NUM1);
  float* den1  = (float*)(ws + OFF_DEN1);
  f16*   gT16  = (f16*)(ws + OFF_GT16);
  float* wc1L  = (float*)(ws + OFF_WC1L);
  float* wc2L  = (float*)(ws + OFF_WC2L);
  float* numc  = (float*)(ws + OFF_NUMC);
  float* denc  = (float*)(ws + OFF_DENC);
  float* tf    = (float*)(ws + OFF_TF);
  float* tg    = (float*)(ws + OFF_TG);

  // zero atomic accumulators (ws is poisoned before every call)
  hipMemsetAsync(wh1, 0, 131328, stream);                         // wh1+wh2+gmax
  hipMemsetAsync(num1, 0, 16842752, stream);                      // num1+den1
  hipMemsetAsync(numc, 0, 4227072, stream);                       // numc+denc

  k_prep   <<<72192, 256, 0, stream>>>((const int4*)adj, maskw, x, x16, head_W, Wt16);
  k_gemm_h <<<dim3(NN/64, DT/128), 256, 0, stream>>>(x16, Wt16, head_a, hT16, wh1, wh2);
  k_rowterms<<<64, 256, 0, stream>>>(wh2, c1, c2, gmax);
  k_agg_head<<<dim3(NN/64, 2, 2), 256, 0, stream>>>(hT16, maskw, wh1, c1, c2, gmax, num1, den1);
  k_merge_conv<<<NN/2, 256, 0, stream>>>(num1, den1, head_b, conv_w, conv_cb, conv_a, gT16, wc1L, wc2L);
  k_agg_conv<<<dim3(NN/64, 8), 256, 0, stream>>>(gT16, maskw, wc1L, wc2L, numc, denc);
  k_mlp    <<<dim3(NN/32, 2), 256, 0, stream>>>(numc, denc, conv_b,
                                                tf_w1, tf_b1, tf_w2, tf_b2,
                                                tg_w1, tg_b1, tg_w2, tg_b2, tf, tg);
  k_pred   <<<EPAIRS/16, 256, 0, stream>>>(ts, (const float4*)tf, (const float4*)tg, outp);
}